// Round 7
// baseline (660.121 us; speedup 1.0000x reference)
//
#include <hip/hip_runtime.h>
#include <hip/hip_bf16.h>
#include <hip/hip_fp16.h>
#include <math.h>

#define Bn 16
#define Nn 2048
#define Cn 128

typedef __attribute__((ext_vector_type(8))) short bf16x8;   // 8 bf16 = 4 VGPRs
typedef __attribute__((ext_vector_type(4))) float f32x4;

// 0.5 / (sqrt(128) * 1.5)  -- folds symmetrization 0.5 and temperature
constexpr float SCALE = 0.029462782549439476f;
constexpr float SHIFT = 4.0f;  // fixed softmax shift; logits bounded well below this +88

__device__ __forceinline__ const bf16x8* as_frag(const void* p){
    return reinterpret_cast<const bf16x8*>(p);
}

// --- fused prep: combined bias (fp16) for all blocks; first 64 blocks also
//     transpose W [d][c] -> WT [c][d] so the projection kernel reads coalesced.
__global__ __launch_bounds__(256) void prep_kernel(
    const float* __restrict__ A, const float* __restrict__ M, __half* __restrict__ CB,
    const float* __restrict__ Wq, const float* __restrict__ Wk,
    float* __restrict__ WqT, float* __restrict__ WkT)
{
    size_t idx = (size_t)blockIdx.x * 256 + threadIdx.x;
    int n = (int)(idx >> 11), m = (int)(idx & (Nn-1));
    float a = A[idx];
    float mm = M[idx];
    float v = (mm <= 0.0f || n == m) ? -INFINITY : a;
    CB[idx] = __float2half(v);
    if (blockIdx.x < 64) {
        int widx = (int)idx;            // 0..16383
        int d = widx >> 7, c = widx & 127;
        WqT[c*Cn + d] = Wq[widx];
        WkT[c*Cn + d] = Wk[widx];
    }
}

// --- Q/K projection: fp32 accumulate, bf16 store. 32 rows per block. ---
__global__ __launch_bounds__(256) void qk_kernel(
    const float* __restrict__ H, const float* __restrict__ WqT, const float* __restrict__ WkT,
    __hip_bfloat16* __restrict__ Qb, __hip_bfloat16* __restrict__ Kb)
{
    __shared__ __align__(16) float Hs[32*Cn];
    const int t = threadIdx.x;
    const size_t row0 = (size_t)blockIdx.x * 32;
    const float4* src = reinterpret_cast<const float4*>(H + row0*Cn);
    float4* dst = reinterpret_cast<float4*>(Hs);
    #pragma unroll
    for (int i = 0; i < 4; i++) dst[i*256 + t] = src[i*256 + t];
    __syncthreads();
    const int d = t & 127, rh = t >> 7;
    float accq[16], acck[16];
    #pragma unroll
    for (int r = 0; r < 16; r++){ accq[r] = 0.f; acck[r] = 0.f; }
    for (int cb = 0; cb < Cn; cb += 4){
        float wq[4], wk[4];
        #pragma unroll
        for (int j = 0; j < 4; j++){ wq[j] = WqT[(cb+j)*Cn + d]; wk[j] = WkT[(cb+j)*Cn + d]; }
        #pragma unroll
        for (int r = 0; r < 16; r++){
            float4 h = *reinterpret_cast<const float4*>(&Hs[(rh*16+r)*Cn + cb]);
            accq[r] += h.x*wq[0] + h.y*wq[1] + h.z*wq[2] + h.w*wq[3];
            acck[r] += h.x*wk[0] + h.y*wk[1] + h.z*wk[2] + h.w*wk[3];
        }
    }
    #pragma unroll
    for (int r = 0; r < 16; r++){
        size_t row = row0 + rh*16 + r;
        Qb[row*Cn + d] = __float2bfloat16(accq[r]);
        Kb[row*Cn + d] = __float2bfloat16(acck[r]);
    }
}

// =====================================================================
// ONE-PASS attention, e in registers. v4: NO LDS STAGING.
// R4 vs R6 showed occupancy/barrier-scope changes are neutral: the cost is
// the staging pipeline itself (32 vmcnt(0)-draining barriers per block, LDS
// used as pure pass-through with no cross-wave reuse). The MFMA B-fragment
// pattern (lane lc reads 16 B of row lc at k-offset ks*64+q*16) coalesces
// fine as a DIRECT global load (16 x 64-B segments per instr, L2-resident
// data). So: load B-fragments straight from global; ZERO barriers in the
// main loop; compiler schedules loads with counted vmcnt on its own.
// Block = 512 threads = 8 waves = 32 rows x 2048 cols;
//   wave = qt*2+rg: qt = 512-col quarter, rg = 16-row group.
// rg-paired waves read identical B bytes -> 2nd reader hits L1.
// Per-thread e = 128 fp16 packed in 64 uints, static indexing (rule #20).
// Single __syncthreads at the cross-quarter rowsum reduce.
// =====================================================================
__global__ __launch_bounds__(512, 2) void attn_onepass_kernel(
    const __hip_bfloat16* __restrict__ Qb, const __hip_bfloat16* __restrict__ Kb,
    const __half* __restrict__ CB, float* __restrict__ out)
{
    __shared__ float psum[4][32];                      // [quarter][row in block]
    const int t = threadIdx.x;
    const int wave = t >> 6, lane = t & 63;
    const int q = lane >> 4, lc = lane & 15;
    const int qt = wave >> 1;          // column quarter 0..3
    const int rg = wave & 1;           // row group 0/1

    // XCD swizzle: consecutive logical blocks (same batch) on one XCD -> that
    // batch's K/Q (1 MB) stays L2-resident. 1024 blocks, %8==0 -> bijective.
    const int h = blockIdx.x;
    const int logical = (h & 7) * 128 + (h >> 3);
    const int bx = logical & 63;       // rowblock 0..63
    const int by = logical >> 6;       // batch 0..15
    const int n0 = bx * 32;
    const size_t rbase = (size_t)by * Nn;

    // A-operand fragments: wave's 16 rows; lane holds row lc, k = ks*32+q*8..+7
    const int nA = n0 + rg*16 + lc;
    bf16x8 aQ[4], aK[4];
    #pragma unroll
    for (int ks = 0; ks < 4; ks++){
        aQ[ks] = *as_frag(Qb + (rbase + nA)*Cn + ks*32 + q*8);
        aK[ks] = *as_frag(Kb + (rbase + nA)*Cn + ks*32 + q*8);
    }

    int nout[4];
    const __half* cbrow[4];
    #pragma unroll
    for (int r = 0; r < 4; r++){
        nout[r] = n0 + rg*16 + q*4 + r;               // C/D row = q*4+reg
        cbrow[r] = CB + (size_t)nout[r]*Nn + qt*512;  // bias row, quarter base
    }

    // B-operand base: row = qt*512 + mc*16 + lc, byte offset ks*64 + q*16
    const char* gK = (const char*)(Kb + (rbase + qt*512 + lc)*Cn) + q*16;
    const char* gQ = (const char*)(Qb + (rbase + qt*512 + lc)*Cn) + q*16;

    unsigned int ep[4][16];            // packed fp16 e: [r][mc>>1], lo=even mc, hi=odd
    float sumacc[4] = {0.f,0.f,0.f,0.f};

    #pragma unroll
    for (int mc = 0; mc < 32; mc++){   // 16 m-cols per iteration, no barriers
        bf16x8 bK[4], bQ[4];
        #pragma unroll
        for (int ks = 0; ks < 4; ks++){
            bK[ks] = *as_frag(gK + mc*4096 + ks*64);   // 16 rows * 256 B per mc
            bQ[ks] = *as_frag(gQ + mc*4096 + ks*64);
        }
        // acc[n][m] = Qn.Km + Kn.Qm  (symmetrization folded in)
        f32x4 acc = {0.f,0.f,0.f,0.f};
        #pragma unroll
        for (int ks = 0; ks < 4; ks++){
            acc = __builtin_amdgcn_mfma_f32_16x16x32_bf16(aQ[ks], bK[ks], acc, 0, 0, 0);
            acc = __builtin_amdgcn_mfma_f32_16x16x32_bf16(aK[ks], bQ[ks], acc, 0, 0, 0);
        }
        const int mq = mc*16 + lc;     // col within quarter
        #pragma unroll
        for (int r = 0; r < 4; r++){
            float logit = fmaf(acc[r], SCALE, __half2float(cbrow[r][mq]));
            float e = __expf(logit - SHIFT);           // -inf -> 0
            sumacc[r] += e;
            unsigned int he = (unsigned int)__half_as_ushort(__float2half(e));
            if ((mc & 1) == 0) ep[r][mc>>1] = he;
            else               ep[r][mc>>1] |= (he << 16);
        }
    }

    // row sums: reduce over lc (16 col-groups) then across the 4 quarters via LDS
    #pragma unroll
    for (int r = 0; r < 4; r++){
        float s = sumacc[r];
        s += __shfl_xor(s, 1);
        s += __shfl_xor(s, 2);
        s += __shfl_xor(s, 4);
        s += __shfl_xor(s, 8);
        if (lc == 0) psum[qt][rg*16 + q*4 + r] = s;
    }
    __syncthreads();
    float rs[4];
    #pragma unroll
    for (int r = 0; r < 4; r++){
        const int rl = rg*16 + q*4 + r;
        rs[r] = 1.0f / (psum[0][rl] + psum[1][rl] + psum[2][rl] + psum[3][rl]);
    }

    // normalize from registers and write out (16-lane groups hit full 64-B lines)
    #pragma unroll
    for (int r = 0; r < 4; r++){
        float* orow = out + (rbase + nout[r])*Nn + qt*512 + lc;
        #pragma unroll
        for (int k = 0; k < 16; k++){
            const unsigned int p = ep[r][k];
            const float elo = __half2float(__ushort_as_half((unsigned short)(p & 0xFFFFu)));
            const float ehi = __half2float(__ushort_as_half((unsigned short)(p >> 16)));
            orow[(2*k)*16]   = elo * rs[r];
            orow[(2*k+1)*16] = ehi * rs[r];
        }
    }
}

// ws layout (bytes):
//   [0,        8388608)    Qb   bf16 [B*N, C]
//   [8388608,  16777216)   Kb   bf16 [B*N, C]
//   [16777216, 16842752)   WqT  fp32 [C, C]
//   [16842752, 16908288)   WkT  fp32 [C, C]
//   [16908288, 25296896)   CB   fp16 [N, N]
extern "C" void kernel_launch(void* const* d_in, const int* in_sizes, int n_in,
                              void* d_out, int out_size, void* d_ws, size_t ws_size,
                              hipStream_t stream)
{
    const float* H  = (const float*)d_in[0];
    const float* A  = (const float*)d_in[1];
    const float* M  = (const float*)d_in[2];
    const float* Wq = (const float*)d_in[3];
    const float* Wk = (const float*)d_in[4];
    float* out = (float*)d_out;
    char* ws = (char*)d_ws;
    __hip_bfloat16* Qb = (__hip_bfloat16*)(ws + 0);
    __hip_bfloat16* Kb = (__hip_bfloat16*)(ws + 8388608);
    float* WqT         = (float*)(ws + 16777216);
    float* WkT         = (float*)(ws + 16842752);
    __half* CB         = (__half*)(ws + 16908288);

    prep_kernel<<<(Nn*Nn)/256, 256, 0, stream>>>(A, M, CB, Wq, Wk, WqT, WkT);
    qk_kernel<<<(Bn*Nn)/32, 256, 0, stream>>>(H, WqT, WkT, Qb, Kb);
    attn_onepass_kernel<<<dim3((Nn/32) * Bn), 512, 0, stream>>>(Qb, Kb, CB, out);
}